// Round 3
// baseline (112.499 us; speedup 1.0000x reference)
//
#include <hip/hip_runtime.h>

// Static config (matches reference)
#define T_Q 8
#define H_Q 16
#define W_Q 16
#define HEADS 8
#define QDIM 64
#define QTOK (T_Q * H_Q * W_Q)   // 2048
#define KTOK 2048                 // T_K*H_K*W_K

typedef float f32x4 __attribute__((ext_vector_type(4)));

// One query row per wave; waves fully independent. No LDS, no __syncthreads.
// q row is loaded via wave-uniform (scalar) loads; rel values are computed
// per-lane and redistributed with __shfl.
__global__ __launch_bounds__(256)
void relpos_fused_kernel(const float* __restrict__ query,   // [B*H*QTOK, QDIM]
                         const float* __restrict__ scores,  // [B*H*QTOK, KTOK]
                         const float* __restrict__ hemb,    // [31, QDIM]
                         const float* __restrict__ wemb,    // [31, QDIM]
                         const float* __restrict__ temb,    // [15, QDIM]
                         float* __restrict__ out)           // [B*H*QTOK, KTOK]
{
    const int tid  = threadIdx.x;
    const int wid  = tid >> 6;          // wave id 0..3
    const int lane = tid & 63;
    // Wave-uniform row index -> q loads become scalar (SMEM) loads.
    const int row  = __builtin_amdgcn_readfirstlane(blockIdx.x * 4 + wid);
    const int qtok = row & (QTOK - 1);
    const int t = (qtok >> 8) & 7;
    const int h = (qtok >> 4) & 15;
    const int w = qtok & 15;

    // Per-lane rel dot product. Lanes 0..15 -> rel_h[hk=lane],
    // 16..31 -> rel_w[wk=lane-16], 32..39 -> rel_t[tk=lane-32],
    // 40..63 -> harmless clamped duplicate (result unused).
    const float* emb;
    if (lane < 16) {
        emb = hemb + (size_t)(h - lane + 15) * QDIM;            // dist = h - hk + 15
    } else if (lane < 32) {
        emb = wemb + (size_t)(w - (lane - 16) + 15) * QDIM;     // dist = w - wk + 15
    } else {
        emb = temb + (size_t)(t - ((lane - 32) & 7) + 7) * QDIM; // dist = t - tk + 7
    }

    const float* qrow = query + (size_t)row * QDIM;  // uniform address
    float a0 = 0.f, a1 = 0.f, a2 = 0.f, a3 = 0.f;
    #pragma unroll
    for (int c = 0; c < QDIM; c += 4) {
        f32x4 e = *reinterpret_cast<const f32x4*>(emb + c);
        a0 += qrow[c]     * e.x;
        a1 += qrow[c + 1] * e.y;
        a2 += qrow[c + 2] * e.z;
        a3 += qrow[c + 3] * e.w;
    }
    const float acc = (a0 + a1) + (a2 + a3);

    // Redistribute: per lane, hk = lane>>2, wk0 = (lane&3)*4, tk = iteration.
    const float rh   = __shfl(acc, lane >> 2, 64);
    const int   wk0  = (lane & 3) * 4;
    const float add0 = rh + __shfl(acc, 16 + wk0 + 0, 64);
    const float add1 = rh + __shfl(acc, 16 + wk0 + 1, 64);
    const float add2 = rh + __shfl(acc, 16 + wk0 + 2, 64);
    const float add3 = rh + __shfl(acc, 16 + wk0 + 3, 64);
    float rt[8];
    #pragma unroll
    for (int it = 0; it < 8; ++it) rt[it] = __shfl(acc, 32 + it, 64);

    // Stream the 2048-float row: 64 lanes x float4 x 8 iterations.
    const size_t base = (size_t)row * KTOK + lane * 4;
    #pragma unroll
    for (int it = 0; it < 8; ++it) {
        const f32x4 s = __builtin_nontemporal_load(
            reinterpret_cast<const f32x4*>(scores + base + it * 256));
        f32x4 o;
        o.x = s.x + add0 + rt[it];
        o.y = s.y + add1 + rt[it];
        o.z = s.z + add2 + rt[it];
        o.w = s.w + add3 + rt[it];
        __builtin_nontemporal_store(o,
            reinterpret_cast<f32x4*>(out + base + it * 256));
    }
}

extern "C" void kernel_launch(void* const* d_in, const int* in_sizes, int n_in,
                              void* d_out, int out_size, void* d_ws, size_t ws_size,
                              hipStream_t stream) {
    const float* query  = (const float*)d_in[0];  // [2,8,2048,64]
    const float* scores = (const float*)d_in[1];  // [2,8,2048,2048]
    const float* hemb   = (const float*)d_in[2];  // [31,64]
    const float* wemb   = (const float*)d_in[3];  // [31,64]
    const float* temb   = (const float*)d_in[4];  // [15,64]
    float* out = (float*)d_out;

    const int B = in_sizes[0] / (HEADS * QTOK * QDIM);   // = 2
    const int rows = B * HEADS * QTOK;                    // 32768

    relpos_fused_kernel<<<rows / 4, 256, 0, stream>>>(query, scores, hemb, wemb, temb, out);
}

// Round 4
// 96.432 us; speedup vs baseline: 1.1666x; 1.1666x over previous
//
#include <hip/hip_runtime.h>

// Static config (matches reference)
#define T_Q 8
#define H_Q 16
#define W_Q 16
#define HEADS 8
#define QDIM 64
#define QTOK (T_Q * H_Q * W_Q)   // 2048
#define KTOK 2048                 // T_K*H_K*W_K

typedef float f32x4 __attribute__((ext_vector_type(4)));

// R1 structure (4 waves/block, one row per wave, LDS + barriers for convoy
// lockstep) with ONE change: the 8 streaming score loads are issued BEFORE
// the prologue, so the barrier's vmcnt(0) drain overlaps q/emb latency with
// stream bandwidth time instead of serializing them.
__global__ __launch_bounds__(256)
void relpos_fused_kernel(const float* __restrict__ query,   // [B*H*QTOK, QDIM]
                         const float* __restrict__ scores,  // [B*H*QTOK, KTOK]
                         const float* __restrict__ hemb,    // [31, QDIM]
                         const float* __restrict__ wemb,    // [31, QDIM]
                         const float* __restrict__ temb,    // [15, QDIM]
                         float* __restrict__ out)           // [B*H*QTOK, KTOK]
{
    const int tid  = threadIdx.x;
    const int wid  = tid >> 6;          // wave id 0..3
    const int lane = tid & 63;
    const int row  = blockIdx.x * 4 + wid;
    const int qtok = row & (QTOK - 1);
    const int t = (qtok >> 8) & 7;
    const int h = (qtok >> 4) & 15;
    const int w = qtok & 15;

    __shared__ float q_s[4][QDIM];
    __shared__ float rel[4][40];        // [0..15]=rel_h, [16..31]=rel_w, [32..39]=rel_t

    // ---- Hoisted stream loads: 8 x NT float4, independent of the prologue.
    const size_t base = (size_t)row * KTOK + lane * 4;
    f32x4 s0 = __builtin_nontemporal_load(reinterpret_cast<const f32x4*>(scores + base + 0 * 256));
    f32x4 s1 = __builtin_nontemporal_load(reinterpret_cast<const f32x4*>(scores + base + 1 * 256));
    f32x4 s2 = __builtin_nontemporal_load(reinterpret_cast<const f32x4*>(scores + base + 2 * 256));
    f32x4 s3 = __builtin_nontemporal_load(reinterpret_cast<const f32x4*>(scores + base + 3 * 256));
    f32x4 s4 = __builtin_nontemporal_load(reinterpret_cast<const f32x4*>(scores + base + 4 * 256));
    f32x4 s5 = __builtin_nontemporal_load(reinterpret_cast<const f32x4*>(scores + base + 5 * 256));
    f32x4 s6 = __builtin_nontemporal_load(reinterpret_cast<const f32x4*>(scores + base + 6 * 256));
    f32x4 s7 = __builtin_nontemporal_load(reinterpret_cast<const f32x4*>(scores + base + 7 * 256));

    // ---- q row: global -> LDS direct (wave-uniform base + lane*4).
    __builtin_amdgcn_global_load_lds(
        reinterpret_cast<const unsigned int*>(query + (size_t)row * QDIM + lane),
        reinterpret_cast<unsigned int*>(&q_s[wid][0]), 4, 0, 0);
    __syncthreads();   // drains q + stream loads; stream BW time hides q latency

    // ---- Lanes 0..39 of EACH wave compute that wave's 40 rel values.
    if (lane < 40) {
        const float* emb;
        if (lane < 16) {
            emb = hemb + (size_t)(h - lane + 15) * QDIM;          // dist = h - hk + 15
        } else if (lane < 32) {
            emb = wemb + (size_t)(w - (lane - 16) + 15) * QDIM;   // dist = w - wk + 15
        } else {
            emb = temb + (size_t)(t - (lane - 32) + 7) * QDIM;    // dist = t - tk + 7
        }
        float a0 = 0.f, a1 = 0.f, a2 = 0.f, a3 = 0.f;
        #pragma unroll
        for (int c = 0; c < QDIM; c += 4) {
            f32x4 e  = *reinterpret_cast<const f32x4*>(emb + c);
            f32x4 qv = *reinterpret_cast<const f32x4*>(&q_s[wid][c]);
            a0 += qv.x * e.x;
            a1 += qv.y * e.y;
            a2 += qv.z * e.z;
            a3 += qv.w * e.w;
        }
        rel[wid][lane] = (a0 + a1) + (a2 + a3);
    }
    __syncthreads();

    // ---- Per-lane invariant rel lookups.
    const float rh   = rel[wid][lane >> 2];
    const int   wk0  = (lane & 3) * 4;
    const float add0 = rh + rel[wid][16 + wk0 + 0];
    const float add1 = rh + rel[wid][16 + wk0 + 1];
    const float add2 = rh + rel[wid][16 + wk0 + 2];
    const float add3 = rh + rel[wid][16 + wk0 + 3];
    float rt[8];
    #pragma unroll
    for (int it = 0; it < 8; ++it) rt[it] = rel[wid][32 + it];

    // ---- Combine + NT stores (data already in registers).
    f32x4 o;
    o.x = s0.x + add0 + rt[0]; o.y = s0.y + add1 + rt[0]; o.z = s0.z + add2 + rt[0]; o.w = s0.w + add3 + rt[0];
    __builtin_nontemporal_store(o, reinterpret_cast<f32x4*>(out + base + 0 * 256));
    o.x = s1.x + add0 + rt[1]; o.y = s1.y + add1 + rt[1]; o.z = s1.z + add2 + rt[1]; o.w = s1.w + add3 + rt[1];
    __builtin_nontemporal_store(o, reinterpret_cast<f32x4*>(out + base + 1 * 256));
    o.x = s2.x + add0 + rt[2]; o.y = s2.y + add1 + rt[2]; o.z = s2.z + add2 + rt[2]; o.w = s2.w + add3 + rt[2];
    __builtin_nontemporal_store(o, reinterpret_cast<f32x4*>(out + base + 2 * 256));
    o.x = s3.x + add0 + rt[3]; o.y = s3.y + add1 + rt[3]; o.z = s3.z + add2 + rt[3]; o.w = s3.w + add3 + rt[3];
    __builtin_nontemporal_store(o, reinterpret_cast<f32x4*>(out + base + 3 * 256));
    o.x = s4.x + add0 + rt[4]; o.y = s4.y + add1 + rt[4]; o.z = s4.z + add2 + rt[4]; o.w = s4.w + add3 + rt[4];
    __builtin_nontemporal_store(o, reinterpret_cast<f32x4*>(out + base + 4 * 256));
    o.x = s5.x + add0 + rt[5]; o.y = s5.y + add1 + rt[5]; o.z = s5.z + add2 + rt[5]; o.w = s5.w + add3 + rt[5];
    __builtin_nontemporal_store(o, reinterpret_cast<f32x4*>(out + base + 5 * 256));
    o.x = s6.x + add0 + rt[6]; o.y = s6.y + add1 + rt[6]; o.z = s6.z + add2 + rt[6]; o.w = s6.w + add3 + rt[6];
    __builtin_nontemporal_store(o, reinterpret_cast<f32x4*>(out + base + 6 * 256));
    o.x = s7.x + add0 + rt[7]; o.y = s7.y + add1 + rt[7]; o.z = s7.z + add2 + rt[7]; o.w = s7.w + add3 + rt[7];
    __builtin_nontemporal_store(o, reinterpret_cast<f32x4*>(out + base + 7 * 256));
}

extern "C" void kernel_launch(void* const* d_in, const int* in_sizes, int n_in,
                              void* d_out, int out_size, void* d_ws, size_t ws_size,
                              hipStream_t stream) {
    const float* query  = (const float*)d_in[0];  // [2,8,2048,64]
    const float* scores = (const float*)d_in[1];  // [2,8,2048,2048]
    const float* hemb   = (const float*)d_in[2];  // [31,64]
    const float* wemb   = (const float*)d_in[3];  // [31,64]
    const float* temb   = (const float*)d_in[4];  // [15,64]
    float* out = (float*)d_out;

    const int B = in_sizes[0] / (HEADS * QTOK * QDIM);   // = 2
    const int rows = B * HEADS * QTOK;                    // 32768

    relpos_fused_kernel<<<rows / 4, 256, 0, stream>>>(query, scores, hemb, wemb, temb, out);
}